// Round 1
// baseline (469.922 us; speedup 1.0000x reference)
//
#include <hip/hip_runtime.h>

typedef unsigned short u16;
typedef __bf16 bf8_t __attribute__((ext_vector_type(8)));
typedef short short8 __attribute__((ext_vector_type(8)));
typedef float f32x4 __attribute__((ext_vector_type(4)));

#define DEV __device__ __forceinline__

DEV u16 f2bf(float x) {
  unsigned u = __builtin_bit_cast(unsigned, x);
  return (u16)((u + 0x7FFFu + ((u >> 16) & 1u)) >> 16);
}
DEV float bf2f(u16 x) {
  unsigned u = (unsigned)x << 16;
  return __builtin_bit_cast(float, u);
}

// ---------------- K0a: pointwise weights fp32 -> bf16, [3][512][512] ----------------
__global__ void k_wconv(const float* __restrict__ f, const float* __restrict__ g,
                        const float* __restrict__ h, u16* __restrict__ out) {
  int i = blockIdx.x * 256 + threadIdx.x;   // 0..786431
  float v;
  if (i < 262144) v = f[i];
  else if (i < 524288) v = g[i - 262144];
  else v = h[i - 524288];
  out[i] = f2bf(v);
}

// ---------------- K0b: style [b][c][n] fp32 -> Xt [b][n][c] bf16 ----------------
__global__ __launch_bounds__(256) void k_xt(const float* __restrict__ style, u16* __restrict__ Xt) {
  __shared__ float t[32][33];
  int b = blockIdx.z, c0 = blockIdx.y * 32, n0 = blockIdx.x * 32;
  int tid = threadIdx.x, lr = tid >> 5, lc = tid & 31;
  const float* src = style + ((size_t)b * 512 + c0) * 4096 + n0;
#pragma unroll
  for (int it = 0; it < 4; ++it) {
    int r = it * 8 + lr;
    t[r][lc] = src[(size_t)r * 4096 + lc];
  }
  __syncthreads();
  u16* dst = Xt + ((size_t)b * 4096 + n0) * 512 + c0;
#pragma unroll
  for (int it = 0; it < 4; ++it) {
    int n = it * 8 + lr;
    dst[(size_t)n * 512 + lc] = f2bf(t[lc][n]);
  }
}

// ---------------- GEMM helpers (128x128 tile, BK=32, 4 waves) ----------------
DEV void gload16(const u16* g, u16* l) {
  __builtin_amdgcn_global_load_lds((__attribute__((address_space(1))) void*)(g),
                                   (__attribute__((address_space(3))) void*)(l), 16, 0, 0);
}

// stage [128 rows][32 k] bf16 tile, row stride 512, into linear LDS [128][32]
DEV void stage_tile(const u16* __restrict__ src, int row0, int kb,
                    u16* lds, int wave, int lane) {
#pragma unroll
  for (int qq = 0; qq < 2; ++qq) {
    int idx = (wave * 2 + qq) * 64 + lane;   // 0..511 16B-chunk id
    int r = idx >> 2;
    int cb = (idx & 3) * 8;
    gload16(src + (size_t)(row0 + r) * 512 + (kb + cb),
            lds + (wave * 2 + qq) * 512);    // wave-uniform base; HW adds lane*16B
  }
}

// ---------------- K1: Y[t][b] = Wbf[t] @ X[b]  (bf16 out) ----------------
__global__ __launch_bounds__(256, 2) void k_gemm_branch(
    const u16* __restrict__ Wbf, const u16* __restrict__ Xt, u16* __restrict__ Y) {
  int z = blockIdx.z;
  int t = z >> 4, b = z & 15;
  const u16* A = Wbf + (size_t)t * (512 * 512);
  const u16* B = Xt + (size_t)b * (4096 * 512);
  u16* C = Y + (size_t)z * (512 * 4096);
  int M0 = blockIdx.y * 128, N0 = blockIdx.x * 128;
  int tid = threadIdx.x, wave = tid >> 6, lane = tid & 63;
  int wm = wave >> 1, wn = wave & 1;
  __shared__ __align__(16) u16 lA[2][128 * 32];
  __shared__ __align__(16) u16 lB[2][128 * 32];
  f32x4 acc[4][4];
#pragma unroll
  for (int m = 0; m < 4; ++m)
#pragma unroll
    for (int n = 0; n < 4; ++n) acc[m][n] = (f32x4){0.f, 0.f, 0.f, 0.f};
  stage_tile(A, M0, 0, &lA[0][0], wave, lane);
  stage_tile(B, N0, 0, &lB[0][0], wave, lane);
  __syncthreads();
  int lrow = lane & 15, lk = (lane >> 4) * 8;
#pragma unroll 2
  for (int kt = 0; kt < 16; ++kt) {
    int cur = kt & 1;
    if (kt < 15) {
      stage_tile(A, M0, (kt + 1) * 32, &lA[cur ^ 1][0], wave, lane);
      stage_tile(B, N0, (kt + 1) * 32, &lB[cur ^ 1][0], wave, lane);
    }
    bf8_t af[4], bff[4];
#pragma unroll
    for (int m = 0; m < 4; ++m)
      af[m] = *(const bf8_t*)&lA[cur][(wm * 64 + m * 16 + lrow) * 32 + lk];
#pragma unroll
    for (int n = 0; n < 4; ++n)
      bff[n] = *(const bf8_t*)&lB[cur][(wn * 64 + n * 16 + lrow) * 32 + lk];
#pragma unroll
    for (int m = 0; m < 4; ++m)
#pragma unroll
      for (int n = 0; n < 4; ++n)
        acc[m][n] = __builtin_amdgcn_mfma_f32_16x16x32_bf16(af[m], bff[n], acc[m][n], 0, 0, 0);
    __syncthreads();
  }
  int orow = (lane >> 4) * 4, ocol = lane & 15;
#pragma unroll
  for (int m = 0; m < 4; ++m)
#pragma unroll
    for (int n = 0; n < 4; ++n) {
      int row = M0 + wm * 64 + m * 16 + orow;
      int col = N0 + wn * 64 + n * 16 + ocol;
      u16* cp = C + (size_t)row * 4096 + col;
#pragma unroll
      for (int i = 0; i < 4; ++i) cp[(size_t)i * 4096] = f2bf(acc[m][n][i]);
    }
}

// ---------------- K2: depthwise 3x3 dil-2 reflect-pad, in place on Y ----------------
__global__ __launch_bounds__(256) void k_dw(u16* __restrict__ Y,
    const float* __restrict__ fwd, const float* __restrict__ gwd, const float* __restrict__ hwd) {
  int p = blockIdx.x;         // (t*16+b)*512 + c
  int c = p & 511;
  int t = p >> 13;            // 8192 planes per branch
  const float* wsrc = (t == 0) ? fwd : (t == 1) ? gwd : hwd;
  __shared__ float w[9];
  __shared__ float pl[4096];
  int tid = threadIdx.x;
  if (tid < 9) w[tid] = wsrc[c * 9 + tid];
  u16* plane = Y + (size_t)p * 4096;
#pragma unroll
  for (int qq = 0; qq < 2; ++qq) {
    int v = tid * 2 + qq;     // 0..511
    short8 d = *(const short8*)(plane + v * 8);
#pragma unroll
    for (int e = 0; e < 8; ++e) pl[v * 8 + e] = bf2f((u16)d[e]);
  }
  __syncthreads();
  int y = tid >> 2, xb = (tid & 3) * 16;
  float o[16];
#pragma unroll
  for (int e = 0; e < 16; ++e) o[e] = 0.f;
#pragma unroll
  for (int i = 0; i < 3; ++i) {
    int yy = y + 2 * i - 2;
    yy = yy < 0 ? -yy : (yy > 63 ? 126 - yy : yy);
    const float* row = pl + yy * 64;
#pragma unroll
    for (int j = 0; j < 3; ++j) {
      float wv = w[i * 3 + j];
#pragma unroll
      for (int e = 0; e < 16; ++e) {
        int xx = xb + e + 2 * j - 2;
        xx = xx < 0 ? -xx : (xx > 63 ? 126 - xx : xx);
        o[e] += wv * row[xx];
      }
    }
  }
  short8 s0, s1;
#pragma unroll
  for (int e = 0; e < 8; ++e) { s0[e] = (short)f2bf(o[e]); s1[e] = (short)f2bf(o[e + 8]); }
  *(short8*)(plane + y * 64 + xb) = s0;
  *(short8*)(plane + y * 64 + xb + 8) = s1;
}

// ---------------- K2b: v [c][n] -> Vt [b][n][c] (bf16) ----------------
__global__ __launch_bounds__(256) void k_vt(const u16* __restrict__ Y, u16* __restrict__ Vt) {
  __shared__ u16 tb[64][72];
  int b = blockIdx.z, c0 = blockIdx.y * 64, n0 = blockIdx.x * 64;
  int tid = threadIdx.x, r = tid >> 2, q = tid & 3;
  const u16* src = Y + ((size_t)(32 + b) * 512 + c0) * 4096 + n0;  // branch 2 = v
  short8 d0 = *(const short8*)(src + (size_t)r * 4096 + q * 16);
  short8 d1 = *(const short8*)(src + (size_t)r * 4096 + q * 16 + 8);
#pragma unroll
  for (int e = 0; e < 8; ++e) { tb[r][q * 16 + e] = (u16)d0[e]; tb[r][q * 16 + 8 + e] = (u16)d1[e]; }
  __syncthreads();
  u16* dst = Vt + ((size_t)b * 4096 + n0) * 512 + c0;
  short8 s0, s1;
#pragma unroll
  for (int e = 0; e < 8; ++e) { s0[e] = (short)tb[q * 16 + e][r]; s1[e] = (short)tb[q * 16 + 8 + e][r]; }
  *(short8*)(dst + (size_t)r * 512 + q * 16) = s0;
  *(short8*)(dst + (size_t)r * 512 + q * 16 + 8) = s1;
}

// ---------------- K3a: energy partials E[part][b][h][64][64] = q@k^T ----------------
__global__ __launch_bounds__(256) void k_energy(const u16* __restrict__ Y, float* __restrict__ E) {
  int half = blockIdx.x, h = blockIdx.y, b = blockIdx.z;
  int tid = threadIdx.x, wave = tid >> 6, lane = tid & 63;
  const u16* q = Y + ((size_t)b * 512 + h * 64) * 4096;          // branch 0 = q
  const u16* k = Y + ((size_t)(16 + b) * 512 + h * 64) * 4096;   // branch 1 = k
  f32x4 acc[4][4];
#pragma unroll
  for (int m = 0; m < 4; ++m)
#pragma unroll
    for (int n = 0; n < 4; ++n) acc[m][n] = (f32x4){0.f, 0.f, 0.f, 0.f};
  int lrow = lane & 15, lk = (lane >> 4) * 8;
  int nstart = half * 1024 + wave * 256;
#pragma unroll 1
  for (int it = 0; it < 8; ++it) {
    int nb = nstart + it * 32;
    bf8_t af[4], bff[4];
#pragma unroll
    for (int m = 0; m < 4; ++m)
      af[m] = *(const bf8_t*)(q + (size_t)(m * 16 + lrow) * 4096 + nb + lk);
#pragma unroll
    for (int n = 0; n < 4; ++n)
      bff[n] = *(const bf8_t*)(k + (size_t)(n * 16 + lrow) * 4096 + nb + lk);
#pragma unroll
    for (int m = 0; m < 4; ++m)
#pragma unroll
      for (int n = 0; n < 4; ++n)
        acc[m][n] = __builtin_amdgcn_mfma_f32_16x16x32_bf16(af[m], bff[n], acc[m][n], 0, 0, 0);
  }
  __shared__ float red[4][4096];
  int orow = (lane >> 4) * 4, ocol = lane & 15;
#pragma unroll
  for (int m = 0; m < 4; ++m)
#pragma unroll
    for (int n = 0; n < 4; ++n)
#pragma unroll
      for (int i = 0; i < 4; ++i)
        red[wave][(m * 16 + orow + i) * 64 + n * 16 + ocol] = acc[m][n][i];
  __syncthreads();
  float* Eo = E + ((size_t)(half * 16 + b) * 8 + h) * 4096;
  for (int v = tid; v < 4096; v += 256)
    Eo[v] = red[0][v] + red[1][v] + red[2][v] + red[3][v];
}

// ---------------- K3s: softmax over d (in place into part 0) ----------------
__global__ __launch_bounds__(64) void k_softmax(float* __restrict__ E, const float* __restrict__ temp) {
  int bh = blockIdx.x;          // b*8+h
  int b = bh >> 3, h = bh & 7;
  int c = threadIdx.x;
  float* p0 = E + (((size_t)b * 8 + h) * 64 + c) * 64;
  float tv = temp[h];
  float e[64];
  float mx = -1e30f;
#pragma unroll
  for (int d = 0; d < 64; ++d) {
    float v = (p0[d] + p0[d + 524288] + p0[d + 1048576] + p0[d + 1572864]) * tv;
    e[d] = v;
    mx = fmaxf(mx, v);
  }
  float s = 0.f;
#pragma unroll
  for (int d = 0; d < 64; ++d) { float v = __expf(e[d] - mx); e[d] = v; s += v; }
  float inv = 1.f / s;
#pragma unroll
  for (int d = 0; d < 64; ++d) p0[d] = e[d] * inv;
}

// ---------------- K3b: M2[b][o][h*64+d] = sum_cc ow[o][h*64+cc]*attn[b][h][cc][d] ----------------
__global__ __launch_bounds__(256) void k_m2(const float* __restrict__ E, const float* __restrict__ ow,
                                            u16* __restrict__ M2) {
  int og = blockIdx.x, h = blockIdx.y, b = blockIdx.z;
  __shared__ float at[4096];
  int tid = threadIdx.x;
  const float* attn = E + ((size_t)b * 8 + h) * 4096;
  for (int v = tid; v < 4096; v += 256) at[v] = attn[v];
  __syncthreads();
  int o = og * 64 + (tid >> 2), dq = (tid & 3) * 16;
  const float* owr = ow + (size_t)o * 512 + h * 64;
  float acc[16];
#pragma unroll
  for (int e = 0; e < 16; ++e) acc[e] = 0.f;
  for (int cc = 0; cc < 64; ++cc) {
    float wv = owr[cc];
#pragma unroll
    for (int e = 0; e < 16; ++e) acc[e] += wv * at[cc * 64 + dq + e];
  }
  u16* dst = M2 + ((size_t)b * 512 + o) * 512 + h * 64 + dq;
  short8 s0, s1;
#pragma unroll
  for (int e = 0; e < 8; ++e) { s0[e] = (short)f2bf(acc[e]); s1[e] = (short)f2bf(acc[e + 8]); }
  *(short8*)dst = s0;
  *(short8*)(dst + 8) = s1;
}

// ---------------- K4: out[b] = M2[b] @ v[b] + style[b]  (fp32 out) ----------------
__global__ __launch_bounds__(256, 2) void k_gemm_final(
    const u16* __restrict__ M2, const u16* __restrict__ Vt,
    const float* __restrict__ style, float* __restrict__ out) {
  int b = blockIdx.z;
  const u16* A = M2 + (size_t)b * (512 * 512);
  const u16* B = Vt + (size_t)b * (4096 * 512);
  const float* st = style + (size_t)b * (512 * 4096);
  float* op = out + (size_t)b * (512 * 4096);
  int M0 = blockIdx.y * 128, N0 = blockIdx.x * 128;
  int tid = threadIdx.x, wave = tid >> 6, lane = tid & 63;
  int wm = wave >> 1, wn = wave & 1;
  __shared__ __align__(16) u16 lA[2][128 * 32];
  __shared__ __align__(16) u16 lB[2][128 * 32];
  f32x4 acc[4][4];
#pragma unroll
  for (int m = 0; m < 4; ++m)
#pragma unroll
    for (int n = 0; n < 4; ++n) acc[m][n] = (f32x4){0.f, 0.f, 0.f, 0.f};
  stage_tile(A, M0, 0, &lA[0][0], wave, lane);
  stage_tile(B, N0, 0, &lB[0][0], wave, lane);
  __syncthreads();
  int lrow = lane & 15, lk = (lane >> 4) * 8;
#pragma unroll 2
  for (int kt = 0; kt < 16; ++kt) {
    int cur = kt & 1;
    if (kt < 15) {
      stage_tile(A, M0, (kt + 1) * 32, &lA[cur ^ 1][0], wave, lane);
      stage_tile(B, N0, (kt + 1) * 32, &lB[cur ^ 1][0], wave, lane);
    }
    bf8_t af[4], bff[4];
#pragma unroll
    for (int m = 0; m < 4; ++m)
      af[m] = *(const bf8_t*)&lA[cur][(wm * 64 + m * 16 + lrow) * 32 + lk];
#pragma unroll
    for (int n = 0; n < 4; ++n)
      bff[n] = *(const bf8_t*)&lB[cur][(wn * 64 + n * 16 + lrow) * 32 + lk];
#pragma unroll
    for (int m = 0; m < 4; ++m)
#pragma unroll
      for (int n = 0; n < 4; ++n)
        acc[m][n] = __builtin_amdgcn_mfma_f32_16x16x32_bf16(af[m], bff[n], acc[m][n], 0, 0, 0);
    __syncthreads();
  }
  int orow = (lane >> 4) * 4, ocol = lane & 15;
#pragma unroll
  for (int m = 0; m < 4; ++m)
#pragma unroll
    for (int n = 0; n < 4; ++n) {
      int row = M0 + wm * 64 + m * 16 + orow;
      int col = N0 + wn * 64 + n * 16 + ocol;
      float* cp = op + (size_t)row * 4096 + col;
      const float* sp = st + (size_t)row * 4096 + col;
#pragma unroll
      for (int i = 0; i < 4; ++i) cp[(size_t)i * 4096] = acc[m][n][i] + sp[(size_t)i * 4096];
    }
}

// ---------------- workspace layout (bytes) ----------------
// Wbf : [3][512][512] bf16            @ 0         (1.5 MB, rounded to 2 MB)
// Y   : [3][16][512][4096] bf16       @ 2 MB      (192 MB)   q,k,v in place after k_dw
// Xt  : [16][4096][512] bf16          @ 203423744 (64 MB)    reused as Vt after K1
// E   : [4][16][8][64][64] f32        @ 270532608 (8 MB)     part0 becomes attn
// M2  : [16][512][512] bf16           @ 278921216 (8 MB)
// total: 287309824 bytes (~274 MB)

extern "C" void kernel_launch(void* const* d_in, const int* in_sizes, int n_in,
                              void* d_out, int out_size, void* d_ws, size_t ws_size,
                              hipStream_t stream) {
  const float* style = (const float*)d_in[0];
  const float* fw1   = (const float*)d_in[1];
  const float* fwd_  = (const float*)d_in[2];
  const float* gw1   = (const float*)d_in[3];
  const float* gwd   = (const float*)d_in[4];
  const float* hw1   = (const float*)d_in[5];
  const float* hwd   = (const float*)d_in[6];
  const float* ow    = (const float*)d_in[7];
  const float* temp  = (const float*)d_in[8];
  float* out = (float*)d_out;

  char* ws = (char*)d_ws;
  u16*   Wbf = (u16*)(ws + 0);
  u16*   Y   = (u16*)(ws + (size_t)2097152);
  u16*   Xt  = (u16*)(ws + (size_t)203423744);
  u16*   Vt  = Xt;                         // reuse: Xt dead after K1, Vt born after K2
  float* E   = (float*)(ws + (size_t)270532608);
  u16*   M2  = (u16*)(ws + (size_t)278921216);

  k_wconv<<<3072, 256, 0, stream>>>(fw1, gw1, hw1, Wbf);
  k_xt<<<dim3(128, 16, 16), 256, 0, stream>>>(style, Xt);
  k_gemm_branch<<<dim3(32, 4, 48), 256, 0, stream>>>(Wbf, Xt, Y);
  k_dw<<<24576, 256, 0, stream>>>(Y, fwd_, gwd, hwd);
  k_vt<<<dim3(64, 8, 16), 256, 0, stream>>>(Y, Vt);
  k_energy<<<dim3(4, 8, 16), 256, 0, stream>>>(Y, E);
  k_softmax<<<128, 64, 0, stream>>>(E, temp);
  k_m2<<<dim3(8, 8, 16), 256, 0, stream>>>(E, ow, M2);
  k_gemm_final<<<dim3(32, 4, 16), 256, 0, stream>>>(M2, Vt, style, out);
}